// Round 12
// baseline (300.024 us; speedup 1.0000x reference)
//
#include <hip/hip_runtime.h>
#include <hip/hip_bf16.h>

// ---------------------------------------------------------------------------
// GAT 2-layer forward. N=50000, E=800000 (+N self loops).
// Round 12: XCD-local aggregation. R11 post-mortem: aggr gather is
// L3-BW-bound (12.8MB h1b > 4MiB per-XCD L2; every XCD streams it from
// Infinity Cache). Fix: block = (4 nodes x 1 head/half slice), slice chosen
// by blockIdx%8 so each XCD touches a 3.2MB slice that FITS its L2.
// L=4 lanes/edge (one 64B line per edge), G=16 edge groups in flight.
// Also: cvt_wall fused into b_count (one fewer launch).
// Fused-score GEMMs, bf16 ew, packed 4B csr, atomic-free binned build.
// Assumes N <= 65536, N % 16 == 0 (and N/4 % 4 == 0 for slice mapping).
// ---------------------------------------------------------------------------

typedef __attribute__((ext_vector_type(8))) short bf16x8;
typedef __attribute__((ext_vector_type(4))) float f32x4;

#define BCHUNK 1024

__device__ __forceinline__ unsigned short f2bf(float f) {
  unsigned x = __float_as_uint(f);
  unsigned r = (x + 0x7fffu + ((x >> 16) & 1u)) >> 16;  // RNE
  return (unsigned short)r;
}
__device__ __forceinline__ float bf2f(unsigned short u) {
  return __uint_as_float(((unsigned)u) << 16);
}
__device__ __forceinline__ float bflo(unsigned u) {
  return __uint_as_float(u << 16);
}
__device__ __forceinline__ float bfhi(unsigned u) {
  return __uint_as_float(u & 0xffff0000u);
}

// inclusive 256-scan in LDS; returns inclusive sum at tid.
__device__ __forceinline__ int lds_scan256(int v, int* s) {
  int tid = threadIdx.x;
  s[tid] = v;
  __syncthreads();
  for (int o = 1; o < 256; o <<= 1) {
    int t = (tid >= o) ? s[tid - o] : 0;
    __syncthreads();
    s[tid] += t;
    __syncthreads();
  }
  return s[tid];
}

// ---- C1 + weight conversion fused ------------------------------------------
// blocks [0,NBLK): per-(block,bucket) histogram -> cnt[blk][256]
// blocks [NBLK, NBLK+112): W1t/W2t transpose-convert + score-weight project
__global__ __launch_bounds__(256) void b_count_cvt(
    const int* __restrict__ ei, int E, int N, int NBLK, int* __restrict__ cnt,
    const float* __restrict__ W1, const float* __restrict__ as1,
    const float* __restrict__ ad1, const float* __restrict__ W2,
    const float* __restrict__ as2, const float* __restrict__ ad2,
    unsigned short* __restrict__ W1t, unsigned short* __restrict__ W2t,
    unsigned short* __restrict__ wsb1, unsigned short* __restrict__ wsb2) {
  int tid = threadIdx.x;
  if ((int)blockIdx.x >= NBLK) {  // conversion blocks
    int i = ((int)blockIdx.x - NBLK) * 256 + tid;
    if (i < 16384) {                       // W1t
      int k = i >> 7, m = i & 127;
      W1t[m * 128 + k] = f2bf(W1[i]);
    } else if (i < 24576) {                // W2t
      int j = i - 16384;
      int k = j / 64, m = j % 64;
      W2t[m * 128 + k] = f2bf(W2[j]);
    } else if (i < 26624) {                // wsb1
      int j = i - 24576;
      int m = j >> 7, k = j & 127;
      float acc = 0.f;
      if (m < 4) {
        for (int c = 0; c < 32; ++c) acc += W1[k * 128 + m * 32 + c] * as1[m * 32 + c];
      } else if (m < 8) {
        for (int c = 0; c < 32; ++c) acc += W1[k * 128 + (m - 4) * 32 + c] * ad1[(m - 4) * 32 + c];
      }
      wsb1[j] = f2bf(acc);
    } else if (i < 28672) {                // wsb2
      int j = i - 26624;
      int m = j >> 7, k = j & 127;
      float acc = 0.f;
      if (m == 0) {
        for (int c = 0; c < 64; ++c) acc += W2[k * 64 + c] * as2[c];
      } else if (m == 1) {
        for (int c = 0; c < 64; ++c) acc += W2[k * 64 + c] * ad2[c];
      }
      wsb2[j] = f2bf(acc);
    }
    return;
  }
  __shared__ int h[256];
  h[tid] = 0;
  __syncthreads();
  int ET = E + N;
  int base = blockIdx.x * BCHUNK;
  int lim = base + BCHUNK;
  if (lim > ET) lim = ET;
  for (int i = base + tid * 4; i < lim; i += 1024) {
    if (i + 3 < E && i + 4 <= lim) {
      int4 d4 = *(const int4*)(ei + E + i);
      atomicAdd(&h[d4.x >> 8], 1);
      atomicAdd(&h[d4.y >> 8], 1);
      atomicAdd(&h[d4.z >> 8], 1);
      atomicAdd(&h[d4.w >> 8], 1);
    } else {
      for (int k = 0; k < 4; ++k) {
        int idx = i + k;
        if (idx < lim) {
          int d = (idx < E) ? ei[E + idx] : (idx - E);
          atomicAdd(&h[d >> 8], 1);
        }
      }
    }
  }
  __syncthreads();
  cnt[(size_t)blockIdx.x * 256 + tid] = h[tid];
}

// ---- MFMA GEMM + fused scores: C[N][M] bf16 = A @ Bt^T; scores = A @ wsb ---
template <int AF32, int SC>
__global__ __launch_bounds__(256) void gemm_mfma(
    const void* __restrict__ Av, const unsigned short* __restrict__ Bt,
    const unsigned short* __restrict__ wsb, unsigned short* __restrict__ C,
    float* __restrict__ ssrc, float* __restrict__ sdst, int N, int M) {
  const int K = 128;
  int lane = threadIdx.x & 63;
  int wv = threadIdx.x >> 6;
  int row0 = blockIdx.x * 64 + wv * 16;
  if (row0 >= N) return;  // N % 16 == 0
  int r = lane & 15, quad = lane >> 4;

  bf16x8 a[4];
  if (AF32) {
    const float* ap = (const float*)Av + (size_t)(row0 + r) * K + quad * 8;
#pragma unroll
    for (int t = 0; t < 4; ++t) {
      float4 lo = *(const float4*)(ap + t * 32);
      float4 hi = *(const float4*)(ap + t * 32 + 4);
      a[t][0] = (short)f2bf(lo.x); a[t][1] = (short)f2bf(lo.y);
      a[t][2] = (short)f2bf(lo.z); a[t][3] = (short)f2bf(lo.w);
      a[t][4] = (short)f2bf(hi.x); a[t][5] = (short)f2bf(hi.y);
      a[t][6] = (short)f2bf(hi.z); a[t][7] = (short)f2bf(hi.w);
    }
  } else {
    const unsigned short* ap = (const unsigned short*)Av + (size_t)(row0 + r) * K + quad * 8;
#pragma unroll
    for (int t = 0; t < 4; ++t) a[t] = *(const bf16x8*)(ap + t * 32);
  }

  for (int c0 = 0; c0 < M; c0 += 16) {
    f32x4 acc = {0.f, 0.f, 0.f, 0.f};
    const unsigned short* bp = Bt + (size_t)(c0 + r) * K + quad * 8;
#pragma unroll
    for (int t = 0; t < 4; ++t) {
      bf16x8 b = *(const bf16x8*)(bp + t * 32);
      acc = __builtin_amdgcn_mfma_f32_16x16x32_bf16(a[t], b, acc, 0, 0, 0);
    }
    unsigned short* cp = C + (size_t)(row0 + quad * 4) * M + c0 + r;
#pragma unroll
    for (int i = 0; i < 4; ++i) cp[(size_t)i * M] = f2bf(acc[i]);
  }

  // fused score tile: cols are wsb rows (0..SC-1 src, SC..2SC-1 dst)
  {
    f32x4 acc = {0.f, 0.f, 0.f, 0.f};
    const unsigned short* bp = wsb + r * 128 + quad * 8;
#pragma unroll
    for (int t = 0; t < 4; ++t) {
      bf16x8 b = *(const bf16x8*)(bp + t * 32);
      acc = __builtin_amdgcn_mfma_f32_16x16x32_bf16(a[t], b, acc, 0, 0, 0);
    }
    int row = row0 + quad * 4;
    if (r < SC) {
#pragma unroll
      for (int i = 0; i < 4; ++i) ssrc[(size_t)(row + i) * SC + r] = acc[i];
    } else if (r < 2 * SC) {
#pragma unroll
      for (int i = 0; i < 4; ++i) sdst[(size_t)(row + i) * SC + (r - SC)] = acc[i];
    }
  }
}

// ---- atomic-free binned CSR build ------------------------------------------
// bucket b covers dst in [b*256, b*256+256); entry packs src | (dst&255)<<16

// C2: per-bucket exclusive scan over blocks: blkoff[blk][bucket], bucketTotal
__global__ __launch_bounds__(256) void b_scan_bkt(const int* __restrict__ cnt, int NBLK,
                                                  int* __restrict__ blkoff,
                                                  int* __restrict__ bucketTotal) {
  __shared__ int s[256];
  int bucket = blockIdx.x, tid = threadIdx.x;
  int carry = 0;
  for (int base = 0; base < NBLK; base += 256) {
    int blk = base + tid;
    int v = (blk < NBLK) ? cnt[(size_t)blk * 256 + bucket] : 0;
    s[tid] = v;
    __syncthreads();
    for (int o = 1; o < 256; o <<= 1) {
      int t = (tid >= o) ? s[tid - o] : 0;
      __syncthreads();
      s[tid] += t;
      __syncthreads();
    }
    if (blk < NBLK) blkoff[(size_t)blk * 256 + bucket] = carry + s[tid] - v;
    carry += s[255];
    __syncthreads();
  }
  if (tid == 0) bucketTotal[bucket] = carry;
}

// C3: scatter packed 4B entries; bucket bases recomputed by inline LDS scan
__global__ __launch_bounds__(256) void b_scatter(
    const int* __restrict__ ei, int E, int N,
    const int* __restrict__ bucketTotal, const int* __restrict__ blkoff,
    unsigned* __restrict__ bkt) {
  __shared__ int s[256];
  __shared__ int lcur[256];
  int tid = threadIdx.x;
  int tot = bucketTotal[tid];
  int incl = lds_scan256(tot, s);
  lcur[tid] = (incl - tot) + blkoff[(size_t)blockIdx.x * 256 + tid];
  __syncthreads();
  int ET = E + N;
  int base = blockIdx.x * BCHUNK;
  int lim = base + BCHUNK;
  if (lim > ET) lim = ET;
  for (int i = base + tid * 4; i < lim; i += 1024) {
    if (i + 3 < E && i + 4 <= lim) {
      int4 s4 = *(const int4*)(ei + i);
      int4 d4 = *(const int4*)(ei + E + i);
      int slot;
      slot = atomicAdd(&lcur[d4.x >> 8], 1); bkt[slot] = (unsigned)s4.x | ((unsigned)(d4.x & 255) << 16);
      slot = atomicAdd(&lcur[d4.y >> 8], 1); bkt[slot] = (unsigned)s4.y | ((unsigned)(d4.y & 255) << 16);
      slot = atomicAdd(&lcur[d4.z >> 8], 1); bkt[slot] = (unsigned)s4.z | ((unsigned)(d4.z & 255) << 16);
      slot = atomicAdd(&lcur[d4.w >> 8], 1); bkt[slot] = (unsigned)s4.w | ((unsigned)(d4.w & 255) << 16);
    } else {
      for (int k = 0; k < 4; ++k) {
        int idx = i + k;
        if (idx < lim) {
          int s_, d;
          if (idx < E) { s_ = ei[idx]; d = ei[E + idx]; }
          else { s_ = idx - E; d = s_; }
          int slot = atomicAdd(&lcur[d >> 8], 1);
          bkt[slot] = (unsigned)s_ | ((unsigned)(d & 255) << 16);
        }
      }
    }
  }
}

// C4: one block per bucket: LDS count+scan over the bucket's 256 nodes,
// coalesced rowptr write, block-local scatter into csr4. 2-deep ILP passes.
__global__ __launch_bounds__(256) void b_bucketsort(
    const unsigned* __restrict__ bkt, const int* __restrict__ bucketTotal,
    unsigned* __restrict__ csr4, int* __restrict__ rowptr, int N, int ET) {
  __shared__ int s[256];
  __shared__ int cnt[256];
  int b = blockIdx.x, tid = threadIdx.x;
  int tot = bucketTotal[tid];
  (void)lds_scan256(tot, s);  // s[i] = inclusive sum
  int base = (b == 0) ? 0 : s[b - 1];
  int end = s[b];
  __syncthreads();
  cnt[tid] = 0;
  __syncthreads();
  for (int i = base + tid; i < end; i += 512) {
    unsigned p0 = bkt[i];
    int i1 = i + 256;
    unsigned p1 = (i1 < end) ? bkt[i1] : 0u;
    atomicAdd(&cnt[p0 >> 16], 1);
    if (i1 < end) atomicAdd(&cnt[p1 >> 16], 1);
  }
  __syncthreads();
  int v = cnt[tid];
  int incl = lds_scan256(v, s);
  int excl = incl - v;
  int node = (b << 8) + tid;
  if (node < N) rowptr[node] = base + excl;
  if (tid == 0 && b == gridDim.x - 1) rowptr[N] = ET;
  cnt[tid] = base + excl;  // becomes the scatter cursor
  __syncthreads();
  for (int i = base + tid; i < end; i += 512) {
    unsigned p0 = bkt[i];
    int i1 = i + 256;
    unsigned p1 = (i1 < end) ? bkt[i1] : 0u;
    int slot0 = atomicAdd(&cnt[p0 >> 16], 1);
    csr4[slot0] = p0;
    if (i1 < end) {
      int slot1 = atomicAdd(&cnt[p1 >> 16], 1);
      csr4[slot1] = p1;
    }
  }
}

// ---- per-(edge,head) softmax weights (bf16), one block per bucket ----------
template <int H>
__global__ __launch_bounds__(256) void k_weightsB(
    const unsigned* __restrict__ csr4, const int* __restrict__ bucketTotal,
    const float* __restrict__ ssrc, const float* __restrict__ sdst,
    unsigned short* __restrict__ ew) {
  __shared__ int s[256];
  int b = blockIdx.x, tid = threadIdx.x;
  int tot = bucketTotal[tid];
  (void)lds_scan256(tot, s);
  int base = (b == 0) ? 0 : s[b - 1];
  int end = s[b];
  __syncthreads();
  for (int i = base + tid; i < end; i += 256) {
    unsigned v = csr4[i];
    int src = v & 0xFFFF;
    int d = (b << 8) | (int)(v >> 16);
    if (H == 4) {
      float4 a = *(const float4*)(ssrc + (size_t)src * 4);
      float4 bb = *(const float4*)(sdst + (size_t)d * 4);
      float sc;
      sc = a.x + bb.x; sc = sc > 0.f ? sc : 0.2f * sc; float w0 = __expf(sc);
      sc = a.y + bb.y; sc = sc > 0.f ? sc : 0.2f * sc; float w1 = __expf(sc);
      sc = a.z + bb.z; sc = sc > 0.f ? sc : 0.2f * sc; float w2 = __expf(sc);
      sc = a.w + bb.w; sc = sc > 0.f ? sc : 0.2f * sc; float w3 = __expf(sc);
      unsigned lo = (unsigned)f2bf(w0) | ((unsigned)f2bf(w1) << 16);
      unsigned hi = (unsigned)f2bf(w2) | ((unsigned)f2bf(w3) << 16);
      *(uint2*)(ew + (size_t)i * 4) = make_uint2(lo, hi);
    } else {
      float sc = ssrc[src] + sdst[d];
      sc = sc > 0.f ? sc : 0.2f * sc;
      ew[i] = f2bf(__expf(sc));
    }
  }
}

// ---- XCD-local aggregator ---------------------------------------------------
// Block = 4 nodes x one 32-channel slice. Slice picked from blockIdx%8 so
// each XCD (blockIdx%8 heuristic) touches a 3.2MB h-slice that fits its L2.
// L=4 lanes/edge (8 ch each, one 64B line), G=16 edge groups, 2-deep pipeline.
// H=4 (layer1): slice = head = (bi&7)>>1; HCT=128; out bf16+ReLU.
// H=1 (layer2): slice = half = (bi&7)>>2; HCT=64; ws identical per half.
template <int H, int OUT_BF16>
__global__ __launch_bounds__(256) void gat_aggr5(
    const int* __restrict__ rowptr, const unsigned* __restrict__ csr4,
    const unsigned short* __restrict__ ew, const unsigned short* __restrict__ h,
    const float* __restrict__ bias, void* __restrict__ outv, int N) {
  const int HCT = (H == 4) ? 128 : 64;
  const int G = 16;
  int bi = blockIdx.x;
  int slice, ng;
  if (H == 4) { slice = (bi & 7) >> 1; ng = (bi >> 3) * 2 + (bi & 1); }
  else        { slice = (bi & 7) >> 2; ng = (bi >> 3) * 4 + (bi & 3); }
  int lane = threadIdx.x & 63;
  int n = ng * 4 + (threadIdx.x >> 6);
  if (n >= N) return;
  int l = lane & 3;
  int g = lane >> 2;
  int c0 = slice * 32 + l * 8;
  int beg = rowptr[n];
  int cnt = rowptr[n + 1] - beg;
  float a0 = 0.f, a1 = 0.f, a2 = 0.f, a3 = 0.f;
  float a4 = 0.f, a5 = 0.f, a6 = 0.f, a7 = 0.f, ws = 0.f;

  int j = g;
  for (; j + G < cnt; j += 2 * G) {
    int i0 = beg + j, i1 = beg + j + G;
    int s0 = (int)(csr4[i0] & 0xFFFF);
    int s1 = (int)(csr4[i1] & 0xFFFF);
    float w0 = bf2f(H == 4 ? ew[(size_t)i0 * 4 + slice] : ew[i0]);
    float w1 = bf2f(H == 4 ? ew[(size_t)i1 * 4 + slice] : ew[i1]);
    uint4 u0 = *(const uint4*)(h + (size_t)s0 * HCT + c0);
    uint4 u1 = *(const uint4*)(h + (size_t)s1 * HCT + c0);
    a0 = fmaf(w0, bflo(u0.x), a0); a1 = fmaf(w0, bfhi(u0.x), a1);
    a2 = fmaf(w0, bflo(u0.y), a2); a3 = fmaf(w0, bfhi(u0.y), a3);
    a4 = fmaf(w0, bflo(u0.z), a4); a5 = fmaf(w0, bfhi(u0.z), a5);
    a6 = fmaf(w0, bflo(u0.w), a6); a7 = fmaf(w0, bfhi(u0.w), a7);
    a0 = fmaf(w1, bflo(u1.x), a0); a1 = fmaf(w1, bfhi(u1.x), a1);
    a2 = fmaf(w1, bflo(u1.y), a2); a3 = fmaf(w1, bfhi(u1.y), a3);
    a4 = fmaf(w1, bflo(u1.z), a4); a5 = fmaf(w1, bfhi(u1.z), a5);
    a6 = fmaf(w1, bflo(u1.w), a6); a7 = fmaf(w1, bfhi(u1.w), a7);
    ws += w0 + w1;
  }
  if (j < cnt) {
    int i0 = beg + j;
    int s0 = (int)(csr4[i0] & 0xFFFF);
    float w0 = bf2f(H == 4 ? ew[(size_t)i0 * 4 + slice] : ew[i0]);
    uint4 u0 = *(const uint4*)(h + (size_t)s0 * HCT + c0);
    a0 = fmaf(w0, bflo(u0.x), a0); a1 = fmaf(w0, bfhi(u0.x), a1);
    a2 = fmaf(w0, bflo(u0.y), a2); a3 = fmaf(w0, bfhi(u0.y), a3);
    a4 = fmaf(w0, bflo(u0.z), a4); a5 = fmaf(w0, bfhi(u0.z), a5);
    a6 = fmaf(w0, bflo(u0.w), a6); a7 = fmaf(w0, bfhi(u0.w), a7);
    ws += w0;
  }
#pragma unroll
  for (int off = 4; off < 64; off <<= 1) {
    a0 += __shfl_xor(a0, off, 64); a1 += __shfl_xor(a1, off, 64);
    a2 += __shfl_xor(a2, off, 64); a3 += __shfl_xor(a3, off, 64);
    a4 += __shfl_xor(a4, off, 64); a5 += __shfl_xor(a5, off, 64);
    a6 += __shfl_xor(a6, off, 64); a7 += __shfl_xor(a7, off, 64);
    ws += __shfl_xor(ws, off, 64);
  }
  if (lane < 4) {
    float inv = 1.f / ws;  // self-loop guarantees ws > 0
    float4 bA = *(const float4*)(bias + c0);
    float4 bB = *(const float4*)(bias + c0 + 4);
    float v0 = fmaf(a0, inv, bA.x), v1 = fmaf(a1, inv, bA.y);
    float v2 = fmaf(a2, inv, bA.z), v3 = fmaf(a3, inv, bA.w);
    float v4 = fmaf(a4, inv, bB.x), v5 = fmaf(a5, inv, bB.y);
    float v6 = fmaf(a6, inv, bB.z), v7 = fmaf(a7, inv, bB.w);
    if (OUT_BF16) {
      v0 = fmaxf(v0, 0.f); v1 = fmaxf(v1, 0.f);
      v2 = fmaxf(v2, 0.f); v3 = fmaxf(v3, 0.f);
      v4 = fmaxf(v4, 0.f); v5 = fmaxf(v5, 0.f);
      v6 = fmaxf(v6, 0.f); v7 = fmaxf(v7, 0.f);
      uint4 o;
      o.x = (unsigned)f2bf(v0) | ((unsigned)f2bf(v1) << 16);
      o.y = (unsigned)f2bf(v2) | ((unsigned)f2bf(v3) << 16);
      o.z = (unsigned)f2bf(v4) | ((unsigned)f2bf(v5) << 16);
      o.w = (unsigned)f2bf(v6) | ((unsigned)f2bf(v7) << 16);
      ((uint4*)outv)[(size_t)n * (HCT / 8) + slice * 4 + l] = o;
    } else {
      float* op = (float*)outv + (size_t)n * HCT + c0;
      *(float4*)op = make_float4(v0, v1, v2, v3);
      *(float4*)(op + 4) = make_float4(v4, v5, v6, v7);
    }
  }
}

extern "C" void kernel_launch(void* const* d_in, const int* in_sizes, int n_in,
                              void* d_out, int out_size, void* d_ws, size_t ws_size,
                              hipStream_t stream) {
  const float* x   = (const float*)d_in[0];
  const int*   ei  = (const int*)d_in[1];
  const float* W1  = (const float*)d_in[2];
  const float* as1 = (const float*)d_in[3];
  const float* ad1 = (const float*)d_in[4];
  const float* b1  = (const float*)d_in[5];
  const float* W2  = (const float*)d_in[6];
  const float* as2 = (const float*)d_in[7];
  const float* ad2 = (const float*)d_in[8];
  const float* b2  = (const float*)d_in[9];

  const int N = in_sizes[0] / 128;  // 50000
  const int E = in_sizes[1] / 2;    // 800000
  const int ET = E + N;
  const int NBKT = (N + 255) >> 8;              // 196
  const int NBLK = (ET + BCHUNK - 1) / BCHUNK;  // 831

  char* pc = (char*)d_ws;
  auto alloc = [&](size_t bytes) -> void* {
    void* r = (void*)pc;
    pc += (bytes + 255) & ~(size_t)255;
    return r;
  };
  unsigned short* h1b   = (unsigned short*)alloc((size_t)N * 128 * 2);  // reused as h2b
  unsigned short* out1b = (unsigned short*)alloc((size_t)N * 128 * 2);
  unsigned short* W1t   = (unsigned short*)alloc(128 * 128 * 2);
  unsigned short* W2t   = (unsigned short*)alloc(64 * 128 * 2);
  unsigned short* wsb1  = (unsigned short*)alloc(16 * 128 * 2);
  unsigned short* wsb2  = (unsigned short*)alloc(16 * 128 * 2);
  float* ssrc1 = (float*)alloc((size_t)N * 4 * 4);
  float* sdst1 = (float*)alloc((size_t)N * 4 * 4);
  float* ssrc2 = (float*)alloc((size_t)N * 4);
  float* sdst2 = (float*)alloc((size_t)N * 4);
  int* rowptr      = (int*)alloc((size_t)(N + 1) * 4);
  int* cnt         = (int*)alloc((size_t)NBLK * 256 * 4);
  int* blkoff      = (int*)alloc((size_t)NBLK * 256 * 4);
  int* bucketTotal = (int*)alloc(256 * 4);
  unsigned* bkt  = (unsigned*)alloc((size_t)ET * 4);
  unsigned* csr4 = (unsigned*)alloc((size_t)ET * 4);
  unsigned short* ew1 = (unsigned short*)alloc((size_t)ET * 4 * 2);
  unsigned short* ew2 = (unsigned short*)alloc((size_t)ET * 2);
  unsigned short* h2b = h1b;  // alias: h1b dead after layer-1 aggregation

  dim3 blk(256);

  // ---- atomic-free binned CSR build + fused weight conversion ----
  b_count_cvt<<<dim3(NBLK + 112), blk, 0, stream>>>(
      ei, E, N, NBLK, cnt, W1, as1, ad1, W2, as2, ad2, W1t, W2t, wsb1, wsb2);
  b_scan_bkt<<<dim3(256), blk, 0, stream>>>(cnt, NBLK, blkoff, bucketTotal);
  b_scatter<<<dim3(NBLK), blk, 0, stream>>>(ei, E, N, bucketTotal, blkoff, bkt);
  b_bucketsort<<<dim3(NBKT), blk, 0, stream>>>(bkt, bucketTotal, csr4, rowptr, N, ET);

  // ---- layer 1: 128 -> 4 heads x 32, concat, +bias, ReLU (scores fused) ----
  gemm_mfma<1, 4><<<dim3((N + 63) / 64), blk, 0, stream>>>(
      x, W1t, wsb1, h1b, ssrc1, sdst1, N, 128);
  k_weightsB<4><<<dim3(NBKT), blk, 0, stream>>>(csr4, bucketTotal, ssrc1, sdst1, ew1);
  // grid = (N/4 node-groups) x 4 heads, XCD-swizzled: needs (N/4)%2==0
  gat_aggr5<4, 1><<<dim3(N), blk, 0, stream>>>(
      rowptr, csr4, ew1, h1b, b1, out1b, N);

  // ---- layer 2: 128 -> 1 head x 64, +bias (scores fused) ----
  gemm_mfma<0, 1><<<dim3((N + 63) / 64), blk, 0, stream>>>(
      out1b, W2t, wsb2, h2b, ssrc2, sdst2, N, 64);
  k_weightsB<1><<<dim3(NBKT), blk, 0, stream>>>(csr4, bucketTotal, ssrc2, sdst2, ew2);
  // grid = (N/4 node-groups) x 2 halves, XCD-swizzled: needs (N/4)%4==0
  gat_aggr5<1, 0><<<dim3(N / 2), blk, 0, stream>>>(
      rowptr, csr4, ew2, h2b, b2, d_out, N);
}

// Round 13
// 236.608 us; speedup vs baseline: 1.2680x; 1.2680x over previous
//
#include <hip/hip_runtime.h>
#include <hip/hip_bf16.h>

// ---------------------------------------------------------------------------
// GAT 2-layer forward. N=50000, E=800000 (+N self loops).
// Round 13: revert of R12's XCD-sliced aggregation (REGRESSED 238.7->300us:
// slicing nodes across 4 blocks multiplied csr/ew metadata reads 4x —
// FETCH 133MB, VALUBusy 73%, plus a pathological 40ms cold-cache dispatch).
// Back to R11 aggregators (one wave/node, uint4 gather, L=16/8), keeping
// R12's b_count_cvt fusion (one fewer launch). Fused-score GEMMs, bf16 ew,
// packed 4B csr, atomic-free binned build. Assumes N <= 65536.
// ---------------------------------------------------------------------------

typedef __attribute__((ext_vector_type(8))) short bf16x8;
typedef __attribute__((ext_vector_type(4))) float f32x4;

#define BCHUNK 1024

__device__ __forceinline__ unsigned short f2bf(float f) {
  unsigned x = __float_as_uint(f);
  unsigned r = (x + 0x7fffu + ((x >> 16) & 1u)) >> 16;  // RNE
  return (unsigned short)r;
}
__device__ __forceinline__ float bf2f(unsigned short u) {
  return __uint_as_float(((unsigned)u) << 16);
}
__device__ __forceinline__ float bflo(unsigned u) {
  return __uint_as_float(u << 16);
}
__device__ __forceinline__ float bfhi(unsigned u) {
  return __uint_as_float(u & 0xffff0000u);
}

// inclusive 256-scan in LDS; returns inclusive sum at tid.
__device__ __forceinline__ int lds_scan256(int v, int* s) {
  int tid = threadIdx.x;
  s[tid] = v;
  __syncthreads();
  for (int o = 1; o < 256; o <<= 1) {
    int t = (tid >= o) ? s[tid - o] : 0;
    __syncthreads();
    s[tid] += t;
    __syncthreads();
  }
  return s[tid];
}

// ---- C1 + weight conversion fused ------------------------------------------
// blocks [0,NBLK): per-(block,bucket) histogram -> cnt[blk][256]
// blocks [NBLK, NBLK+112): W1t/W2t transpose-convert + score-weight project
__global__ __launch_bounds__(256) void b_count_cvt(
    const int* __restrict__ ei, int E, int N, int NBLK, int* __restrict__ cnt,
    const float* __restrict__ W1, const float* __restrict__ as1,
    const float* __restrict__ ad1, const float* __restrict__ W2,
    const float* __restrict__ as2, const float* __restrict__ ad2,
    unsigned short* __restrict__ W1t, unsigned short* __restrict__ W2t,
    unsigned short* __restrict__ wsb1, unsigned short* __restrict__ wsb2) {
  int tid = threadIdx.x;
  if ((int)blockIdx.x >= NBLK) {  // conversion blocks
    int i = ((int)blockIdx.x - NBLK) * 256 + tid;
    if (i < 16384) {                       // W1t
      int k = i >> 7, m = i & 127;
      W1t[m * 128 + k] = f2bf(W1[i]);
    } else if (i < 24576) {                // W2t
      int j = i - 16384;
      int k = j / 64, m = j % 64;
      W2t[m * 128 + k] = f2bf(W2[j]);
    } else if (i < 26624) {                // wsb1
      int j = i - 24576;
      int m = j >> 7, k = j & 127;
      float acc = 0.f;
      if (m < 4) {
        for (int c = 0; c < 32; ++c) acc += W1[k * 128 + m * 32 + c] * as1[m * 32 + c];
      } else if (m < 8) {
        for (int c = 0; c < 32; ++c) acc += W1[k * 128 + (m - 4) * 32 + c] * ad1[(m - 4) * 32 + c];
      }
      wsb1[j] = f2bf(acc);
    } else if (i < 28672) {                // wsb2
      int j = i - 26624;
      int m = j >> 7, k = j & 127;
      float acc = 0.f;
      if (m == 0) {
        for (int c = 0; c < 64; ++c) acc += W2[k * 64 + c] * as2[c];
      } else if (m == 1) {
        for (int c = 0; c < 64; ++c) acc += W2[k * 64 + c] * ad2[c];
      }
      wsb2[j] = f2bf(acc);
    }
    return;
  }
  __shared__ int h[256];
  h[tid] = 0;
  __syncthreads();
  int ET = E + N;
  int base = blockIdx.x * BCHUNK;
  int lim = base + BCHUNK;
  if (lim > ET) lim = ET;
  for (int i = base + tid * 4; i < lim; i += 1024) {
    if (i + 3 < E && i + 4 <= lim) {
      int4 d4 = *(const int4*)(ei + E + i);
      atomicAdd(&h[d4.x >> 8], 1);
      atomicAdd(&h[d4.y >> 8], 1);
      atomicAdd(&h[d4.z >> 8], 1);
      atomicAdd(&h[d4.w >> 8], 1);
    } else {
      for (int k = 0; k < 4; ++k) {
        int idx = i + k;
        if (idx < lim) {
          int d = (idx < E) ? ei[E + idx] : (idx - E);
          atomicAdd(&h[d >> 8], 1);
        }
      }
    }
  }
  __syncthreads();
  cnt[(size_t)blockIdx.x * 256 + tid] = h[tid];
}

// ---- MFMA GEMM + fused scores: C[N][M] bf16 = A @ Bt^T; scores = A @ wsb ---
template <int AF32, int SC>
__global__ __launch_bounds__(256) void gemm_mfma(
    const void* __restrict__ Av, const unsigned short* __restrict__ Bt,
    const unsigned short* __restrict__ wsb, unsigned short* __restrict__ C,
    float* __restrict__ ssrc, float* __restrict__ sdst, int N, int M) {
  const int K = 128;
  int lane = threadIdx.x & 63;
  int wv = threadIdx.x >> 6;
  int row0 = blockIdx.x * 64 + wv * 16;
  if (row0 >= N) return;  // N % 16 == 0
  int r = lane & 15, quad = lane >> 4;

  bf16x8 a[4];
  if (AF32) {
    const float* ap = (const float*)Av + (size_t)(row0 + r) * K + quad * 8;
#pragma unroll
    for (int t = 0; t < 4; ++t) {
      float4 lo = *(const float4*)(ap + t * 32);
      float4 hi = *(const float4*)(ap + t * 32 + 4);
      a[t][0] = (short)f2bf(lo.x); a[t][1] = (short)f2bf(lo.y);
      a[t][2] = (short)f2bf(lo.z); a[t][3] = (short)f2bf(lo.w);
      a[t][4] = (short)f2bf(hi.x); a[t][5] = (short)f2bf(hi.y);
      a[t][6] = (short)f2bf(hi.z); a[t][7] = (short)f2bf(hi.w);
    }
  } else {
    const unsigned short* ap = (const unsigned short*)Av + (size_t)(row0 + r) * K + quad * 8;
#pragma unroll
    for (int t = 0; t < 4; ++t) a[t] = *(const bf16x8*)(ap + t * 32);
  }

  for (int c0 = 0; c0 < M; c0 += 16) {
    f32x4 acc = {0.f, 0.f, 0.f, 0.f};
    const unsigned short* bp = Bt + (size_t)(c0 + r) * K + quad * 8;
#pragma unroll
    for (int t = 0; t < 4; ++t) {
      bf16x8 b = *(const bf16x8*)(bp + t * 32);
      acc = __builtin_amdgcn_mfma_f32_16x16x32_bf16(a[t], b, acc, 0, 0, 0);
    }
    unsigned short* cp = C + (size_t)(row0 + quad * 4) * M + c0 + r;
#pragma unroll
    for (int i = 0; i < 4; ++i) cp[(size_t)i * M] = f2bf(acc[i]);
  }

  // fused score tile: cols are wsb rows (0..SC-1 src, SC..2SC-1 dst)
  {
    f32x4 acc = {0.f, 0.f, 0.f, 0.f};
    const unsigned short* bp = wsb + r * 128 + quad * 8;
#pragma unroll
    for (int t = 0; t < 4; ++t) {
      bf16x8 b = *(const bf16x8*)(bp + t * 32);
      acc = __builtin_amdgcn_mfma_f32_16x16x32_bf16(a[t], b, acc, 0, 0, 0);
    }
    int row = row0 + quad * 4;
    if (r < SC) {
#pragma unroll
      for (int i = 0; i < 4; ++i) ssrc[(size_t)(row + i) * SC + r] = acc[i];
    } else if (r < 2 * SC) {
#pragma unroll
      for (int i = 0; i < 4; ++i) sdst[(size_t)(row + i) * SC + (r - SC)] = acc[i];
    }
  }
}

// ---- atomic-free binned CSR build ------------------------------------------
// bucket b covers dst in [b*256, b*256+256); entry packs src | (dst&255)<<16

// C2: per-bucket exclusive scan over blocks: blkoff[blk][bucket], bucketTotal
__global__ __launch_bounds__(256) void b_scan_bkt(const int* __restrict__ cnt, int NBLK,
                                                  int* __restrict__ blkoff,
                                                  int* __restrict__ bucketTotal) {
  __shared__ int s[256];
  int bucket = blockIdx.x, tid = threadIdx.x;
  int carry = 0;
  for (int base = 0; base < NBLK; base += 256) {
    int blk = base + tid;
    int v = (blk < NBLK) ? cnt[(size_t)blk * 256 + bucket] : 0;
    s[tid] = v;
    __syncthreads();
    for (int o = 1; o < 256; o <<= 1) {
      int t = (tid >= o) ? s[tid - o] : 0;
      __syncthreads();
      s[tid] += t;
      __syncthreads();
    }
    if (blk < NBLK) blkoff[(size_t)blk * 256 + bucket] = carry + s[tid] - v;
    carry += s[255];
    __syncthreads();
  }
  if (tid == 0) bucketTotal[bucket] = carry;
}

// C3: scatter packed 4B entries; bucket bases recomputed by inline LDS scan
__global__ __launch_bounds__(256) void b_scatter(
    const int* __restrict__ ei, int E, int N,
    const int* __restrict__ bucketTotal, const int* __restrict__ blkoff,
    unsigned* __restrict__ bkt) {
  __shared__ int s[256];
  __shared__ int lcur[256];
  int tid = threadIdx.x;
  int tot = bucketTotal[tid];
  int incl = lds_scan256(tot, s);
  lcur[tid] = (incl - tot) + blkoff[(size_t)blockIdx.x * 256 + tid];
  __syncthreads();
  int ET = E + N;
  int base = blockIdx.x * BCHUNK;
  int lim = base + BCHUNK;
  if (lim > ET) lim = ET;
  for (int i = base + tid * 4; i < lim; i += 1024) {
    if (i + 3 < E && i + 4 <= lim) {
      int4 s4 = *(const int4*)(ei + i);
      int4 d4 = *(const int4*)(ei + E + i);
      int slot;
      slot = atomicAdd(&lcur[d4.x >> 8], 1); bkt[slot] = (unsigned)s4.x | ((unsigned)(d4.x & 255) << 16);
      slot = atomicAdd(&lcur[d4.y >> 8], 1); bkt[slot] = (unsigned)s4.y | ((unsigned)(d4.y & 255) << 16);
      slot = atomicAdd(&lcur[d4.z >> 8], 1); bkt[slot] = (unsigned)s4.z | ((unsigned)(d4.z & 255) << 16);
      slot = atomicAdd(&lcur[d4.w >> 8], 1); bkt[slot] = (unsigned)s4.w | ((unsigned)(d4.w & 255) << 16);
    } else {
      for (int k = 0; k < 4; ++k) {
        int idx = i + k;
        if (idx < lim) {
          int s_, d;
          if (idx < E) { s_ = ei[idx]; d = ei[E + idx]; }
          else { s_ = idx - E; d = s_; }
          int slot = atomicAdd(&lcur[d >> 8], 1);
          bkt[slot] = (unsigned)s_ | ((unsigned)(d & 255) << 16);
        }
      }
    }
  }
}

// C4: one block per bucket: LDS count+scan over the bucket's 256 nodes,
// coalesced rowptr write, block-local scatter into csr4. 2-deep ILP passes.
__global__ __launch_bounds__(256) void b_bucketsort(
    const unsigned* __restrict__ bkt, const int* __restrict__ bucketTotal,
    unsigned* __restrict__ csr4, int* __restrict__ rowptr, int N, int ET) {
  __shared__ int s[256];
  __shared__ int cnt[256];
  int b = blockIdx.x, tid = threadIdx.x;
  int tot = bucketTotal[tid];
  (void)lds_scan256(tot, s);  // s[i] = inclusive sum
  int base = (b == 0) ? 0 : s[b - 1];
  int end = s[b];
  __syncthreads();
  cnt[tid] = 0;
  __syncthreads();
  for (int i = base + tid; i < end; i += 512) {
    unsigned p0 = bkt[i];
    int i1 = i + 256;
    unsigned p1 = (i1 < end) ? bkt[i1] : 0u;
    atomicAdd(&cnt[p0 >> 16], 1);
    if (i1 < end) atomicAdd(&cnt[p1 >> 16], 1);
  }
  __syncthreads();
  int v = cnt[tid];
  int incl = lds_scan256(v, s);
  int excl = incl - v;
  int node = (b << 8) + tid;
  if (node < N) rowptr[node] = base + excl;
  if (tid == 0 && b == gridDim.x - 1) rowptr[N] = ET;
  cnt[tid] = base + excl;  // becomes the scatter cursor
  __syncthreads();
  for (int i = base + tid; i < end; i += 512) {
    unsigned p0 = bkt[i];
    int i1 = i + 256;
    unsigned p1 = (i1 < end) ? bkt[i1] : 0u;
    int slot0 = atomicAdd(&cnt[p0 >> 16], 1);
    csr4[slot0] = p0;
    if (i1 < end) {
      int slot1 = atomicAdd(&cnt[p1 >> 16], 1);
      csr4[slot1] = p1;
    }
  }
}

// ---- per-(edge,head) softmax weights (bf16), one block per bucket ----------
template <int H>
__global__ __launch_bounds__(256) void k_weightsB(
    const unsigned* __restrict__ csr4, const int* __restrict__ bucketTotal,
    const float* __restrict__ ssrc, const float* __restrict__ sdst,
    unsigned short* __restrict__ ew) {
  __shared__ int s[256];
  int b = blockIdx.x, tid = threadIdx.x;
  int tot = bucketTotal[tid];
  (void)lds_scan256(tot, s);
  int base = (b == 0) ? 0 : s[b - 1];
  int end = s[b];
  __syncthreads();
  for (int i = base + tid; i < end; i += 256) {
    unsigned v = csr4[i];
    int src = v & 0xFFFF;
    int d = (b << 8) | (int)(v >> 16);
    if (H == 4) {
      float4 a = *(const float4*)(ssrc + (size_t)src * 4);
      float4 bb = *(const float4*)(sdst + (size_t)d * 4);
      float sc;
      sc = a.x + bb.x; sc = sc > 0.f ? sc : 0.2f * sc; float w0 = __expf(sc);
      sc = a.y + bb.y; sc = sc > 0.f ? sc : 0.2f * sc; float w1 = __expf(sc);
      sc = a.z + bb.z; sc = sc > 0.f ? sc : 0.2f * sc; float w2 = __expf(sc);
      sc = a.w + bb.w; sc = sc > 0.f ? sc : 0.2f * sc; float w3 = __expf(sc);
      unsigned lo = (unsigned)f2bf(w0) | ((unsigned)f2bf(w1) << 16);
      unsigned hi = (unsigned)f2bf(w2) | ((unsigned)f2bf(w3) << 16);
      *(uint2*)(ew + (size_t)i * 4) = make_uint2(lo, hi);
    } else {
      float sc = ssrc[src] + sdst[d];
      sc = sc > 0.f ? sc : 0.2f * sc;
      ew[i] = f2bf(__expf(sc));
    }
  }
}

// ---- aggregator: out[n] = (sum_e w_e * h[src_e]) / (sum_e w_e) + bias -------
// One wave per dst node. L lanes/edge, 8 bf16 channels/lane (uint4 gather);
// G=64/L edge groups in flight. Cross-group combine via shfl_xor butterfly.
template <int H, int C, int L, int OUT_BF16>
__global__ __launch_bounds__(256) void gat_aggr4(
    const int* __restrict__ rowptr, const unsigned* __restrict__ csr4,
    const unsigned short* __restrict__ ew, const unsigned short* __restrict__ h,
    const float* __restrict__ bias, void* __restrict__ outv, int N) {
  const int HC = H * C;  // = 8*L
  const int G = 64 / L;
  int lane = threadIdx.x & 63;
  int n = blockIdx.x * 4 + (threadIdx.x >> 6);
  if (n >= N) return;
  int l = lane & (L - 1);
  int g = lane / L;
  int c0 = l * 8;
  int hh = c0 / C;
  int beg = rowptr[n];
  int cnt = rowptr[n + 1] - beg;
  float a0 = 0.f, a1 = 0.f, a2 = 0.f, a3 = 0.f;
  float a4 = 0.f, a5 = 0.f, a6 = 0.f, a7 = 0.f, ws = 0.f;

  int j = g;
  for (; j + G < cnt; j += 2 * G) {
    int i0 = beg + j, i1 = beg + j + G;
    int s0 = (int)(csr4[i0] & 0xFFFF);
    int s1 = (int)(csr4[i1] & 0xFFFF);
    float w0 = bf2f(ew[(size_t)i0 * H + hh]);
    float w1 = bf2f(ew[(size_t)i1 * H + hh]);
    uint4 u0 = *(const uint4*)(h + (size_t)s0 * HC + c0);
    uint4 u1 = *(const uint4*)(h + (size_t)s1 * HC + c0);
    a0 = fmaf(w0, bflo(u0.x), a0); a1 = fmaf(w0, bfhi(u0.x), a1);
    a2 = fmaf(w0, bflo(u0.y), a2); a3 = fmaf(w0, bfhi(u0.y), a3);
    a4 = fmaf(w0, bflo(u0.z), a4); a5 = fmaf(w0, bfhi(u0.z), a5);
    a6 = fmaf(w0, bflo(u0.w), a6); a7 = fmaf(w0, bfhi(u0.w), a7);
    a0 = fmaf(w1, bflo(u1.x), a0); a1 = fmaf(w1, bfhi(u1.x), a1);
    a2 = fmaf(w1, bflo(u1.y), a2); a3 = fmaf(w1, bfhi(u1.y), a3);
    a4 = fmaf(w1, bflo(u1.z), a4); a5 = fmaf(w1, bfhi(u1.z), a5);
    a6 = fmaf(w1, bflo(u1.w), a6); a7 = fmaf(w1, bfhi(u1.w), a7);
    ws += w0 + w1;
  }
  if (j < cnt) {
    int i0 = beg + j;
    int s0 = (int)(csr4[i0] & 0xFFFF);
    float w0 = bf2f(ew[(size_t)i0 * H + hh]);
    uint4 u0 = *(const uint4*)(h + (size_t)s0 * HC + c0);
    a0 = fmaf(w0, bflo(u0.x), a0); a1 = fmaf(w0, bfhi(u0.x), a1);
    a2 = fmaf(w0, bflo(u0.y), a2); a3 = fmaf(w0, bfhi(u0.y), a3);
    a4 = fmaf(w0, bflo(u0.z), a4); a5 = fmaf(w0, bfhi(u0.z), a5);
    a6 = fmaf(w0, bflo(u0.w), a6); a7 = fmaf(w0, bfhi(u0.w), a7);
    ws += w0;
  }
#pragma unroll
  for (int off = L; off < 64; off <<= 1) {
    a0 += __shfl_xor(a0, off, 64); a1 += __shfl_xor(a1, off, 64);
    a2 += __shfl_xor(a2, off, 64); a3 += __shfl_xor(a3, off, 64);
    a4 += __shfl_xor(a4, off, 64); a5 += __shfl_xor(a5, off, 64);
    a6 += __shfl_xor(a6, off, 64); a7 += __shfl_xor(a7, off, 64);
    ws += __shfl_xor(ws, off, 64);
  }
  if (lane < L) {
    float inv = 1.f / ws;  // self-loop guarantees ws > 0
    float4 bA = *(const float4*)(bias + c0);
    float4 bB = *(const float4*)(bias + c0 + 4);
    float v0 = fmaf(a0, inv, bA.x), v1 = fmaf(a1, inv, bA.y);
    float v2 = fmaf(a2, inv, bA.z), v3 = fmaf(a3, inv, bA.w);
    float v4 = fmaf(a4, inv, bB.x), v5 = fmaf(a5, inv, bB.y);
    float v6 = fmaf(a6, inv, bB.z), v7 = fmaf(a7, inv, bB.w);
    if (OUT_BF16) {
      v0 = fmaxf(v0, 0.f); v1 = fmaxf(v1, 0.f);
      v2 = fmaxf(v2, 0.f); v3 = fmaxf(v3, 0.f);
      v4 = fmaxf(v4, 0.f); v5 = fmaxf(v5, 0.f);
      v6 = fmaxf(v6, 0.f); v7 = fmaxf(v7, 0.f);
      uint4 o;
      o.x = (unsigned)f2bf(v0) | ((unsigned)f2bf(v1) << 16);
      o.y = (unsigned)f2bf(v2) | ((unsigned)f2bf(v3) << 16);
      o.z = (unsigned)f2bf(v4) | ((unsigned)f2bf(v5) << 16);
      o.w = (unsigned)f2bf(v6) | ((unsigned)f2bf(v7) << 16);
      ((uint4*)outv)[(size_t)n * (HC / 8) + l] = o;
    } else {
      float* op = (float*)outv + (size_t)n * HC + c0;
      *(float4*)op = make_float4(v0, v1, v2, v3);
      *(float4*)(op + 4) = make_float4(v4, v5, v6, v7);
    }
  }
}

extern "C" void kernel_launch(void* const* d_in, const int* in_sizes, int n_in,
                              void* d_out, int out_size, void* d_ws, size_t ws_size,
                              hipStream_t stream) {
  const float* x   = (const float*)d_in[0];
  const int*   ei  = (const int*)d_in[1];
  const float* W1  = (const float*)d_in[2];
  const float* as1 = (const float*)d_in[3];
  const float* ad1 = (const float*)d_in[4];
  const float* b1  = (const float*)d_in[5];
  const float* W2  = (const float*)d_in[6];
  const float* as2 = (const float*)d_in[7];
  const float* ad2 = (const float*)d_in[8];
  const float* b2  = (const float*)d_in[9];

  const int N = in_sizes[0] / 128;  // 50000
  const int E = in_sizes[1] / 2;    // 800000
  const int ET = E + N;
  const int NBKT = (N + 255) >> 8;              // 196
  const int NBLK = (ET + BCHUNK - 1) / BCHUNK;  // 831

  char* pc = (char*)d_ws;
  auto alloc = [&](size_t bytes) -> void* {
    void* r = (void*)pc;
    pc += (bytes + 255) & ~(size_t)255;
    return r;
  };
  unsigned short* h1b   = (unsigned short*)alloc((size_t)N * 128 * 2);  // reused as h2b
  unsigned short* out1b = (unsigned short*)alloc((size_t)N * 128 * 2);
  unsigned short* W1t   = (unsigned short*)alloc(128 * 128 * 2);
  unsigned short* W2t   = (unsigned short*)alloc(64 * 128 * 2);
  unsigned short* wsb1  = (unsigned short*)alloc(16 * 128 * 2);
  unsigned short* wsb2  = (unsigned short*)alloc(16 * 128 * 2);
  float* ssrc1 = (float*)alloc((size_t)N * 4 * 4);
  float* sdst1 = (float*)alloc((size_t)N * 4 * 4);
  float* ssrc2 = (float*)alloc((size_t)N * 4);
  float* sdst2 = (float*)alloc((size_t)N * 4);
  int* rowptr      = (int*)alloc((size_t)(N + 1) * 4);
  int* cnt         = (int*)alloc((size_t)NBLK * 256 * 4);
  int* blkoff      = (int*)alloc((size_t)NBLK * 256 * 4);
  int* bucketTotal = (int*)alloc(256 * 4);
  unsigned* bkt  = (unsigned*)alloc((size_t)ET * 4);
  unsigned* csr4 = (unsigned*)alloc((size_t)ET * 4);
  unsigned short* ew1 = (unsigned short*)alloc((size_t)ET * 4 * 2);
  unsigned short* ew2 = (unsigned short*)alloc((size_t)ET * 2);
  unsigned short* h2b = h1b;  // alias: h1b dead after layer-1 aggregation

  dim3 blk(256);

  // ---- atomic-free binned CSR build + fused weight conversion ----
  b_count_cvt<<<dim3(NBLK + 112), blk, 0, stream>>>(
      ei, E, N, NBLK, cnt, W1, as1, ad1, W2, as2, ad2, W1t, W2t, wsb1, wsb2);
  b_scan_bkt<<<dim3(256), blk, 0, stream>>>(cnt, NBLK, blkoff, bucketTotal);
  b_scatter<<<dim3(NBLK), blk, 0, stream>>>(ei, E, N, bucketTotal, blkoff, bkt);
  b_bucketsort<<<dim3(NBKT), blk, 0, stream>>>(bkt, bucketTotal, csr4, rowptr, N, ET);

  // ---- layer 1: 128 -> 4 heads x 32, concat, +bias, ReLU (scores fused) ----
  gemm_mfma<1, 4><<<dim3((N + 63) / 64), blk, 0, stream>>>(
      x, W1t, wsb1, h1b, ssrc1, sdst1, N, 128);
  k_weightsB<4><<<dim3(NBKT), blk, 0, stream>>>(csr4, bucketTotal, ssrc1, sdst1, ew1);
  gat_aggr4<4, 32, 16, 1><<<dim3((N + 3) / 4), blk, 0, stream>>>(
      rowptr, csr4, ew1, h1b, b1, out1b, N);

  // ---- layer 2: 128 -> 1 head x 64, +bias (scores fused) ----
  gemm_mfma<0, 1><<<dim3((N + 63) / 64), blk, 0, stream>>>(
      out1b, W2t, wsb2, h2b, ssrc2, sdst2, N, 64);
  k_weightsB<1><<<dim3(NBKT), blk, 0, stream>>>(csr4, bucketTotal, ssrc2, sdst2, ew2);
  gat_aggr4<1, 64, 8, 0><<<dim3((N + 3) / 4), blk, 0, stream>>>(
      rowptr, csr4, ew2, h2b, b2, d_out, N);
}